// Round 6
// baseline (670.656 us; speedup 1.0000x reference)
//
#include <hip/hip_runtime.h>
#include <math.h>

// GAT pipeline. bf16-packed z/hnei/z2; no-max softmax; MFMA for both GEMMs;
// gat1 = wave-per-dst with 4-edge-parallel gather; gat2 = edge-parallel
// (precomputed alphas) reduced straight to the global mean.

#define CAP 128   // per-wave LDS edge cache; deg>CAP falls back to recompute

typedef unsigned int  uint_t;
typedef unsigned short ushort_t;
typedef __attribute__((ext_vector_type(8))) short short8;
typedef __attribute__((ext_vector_type(4))) float floatx4;

__device__ __forceinline__ float wred_sum(float v){
#pragma unroll
  for (int o = 1; o < 64; o <<= 1) v += __shfl_xor(v, o, 64);
  return v;
}
__device__ __forceinline__ float lrelu(float x){ return x >= 0.f ? x : 0.01f*x; }
__device__ __forceinline__ ushort_t f2b(float f){
  uint_t u = __float_as_uint(f);
  u = (u + 0x7FFFu + ((u >> 16) & 1u)) >> 16;   // RNE
  return (ushort_t)u;
}
__device__ __forceinline__ float b2f_lo(uint_t w){ return __uint_as_float(w << 16); }
__device__ __forceinline__ float b2f_hi(uint_t w){ return __uint_as_float(w & 0xFFFF0000u); }

// ---------------- pack W1 (32768) + W2 (16384) into MFMA B-frag order, one kernel
__global__ void k_wpack(const float* __restrict__ W1, const float* __restrict__ W2,
                        ushort_t* __restrict__ w1bp, ushort_t* __restrict__ w2bp){
  int idx = blockIdx.x*256 + threadIdx.x;
  if (idx < 32768){
    int j = idx & 7, lane = (idx >> 3) & 63, ks = (idx >> 9) & 3, t = idx >> 11;
    int n = t*16 + (lane & 15), k = ks*32 + (lane >> 4)*8 + j;
    w1bp[idx] = f2b(W1[n*128 + k]);
  } else if (idx < 49152){
    int i2 = idx - 32768;
    int j = i2 & 7, lane = (i2 >> 3) & 63, ks = (i2 >> 9) & 7, t = i2 >> 12;
    int n = t*16 + (lane & 15), k = ks*32 + (lane >> 4)*8 + j;
    w2bp[i2] = f2b(W2[n*256 + k]);
  }
}

// ---------------- GEMM1 (MFMA, split-A): zb[N][64] uint2 + layer1 scores
__global__ __launch_bounds__(256) void k_gemm1m(const float* __restrict__ h,
    const ushort_t* __restrict__ w1bp, const float* __restrict__ a1,
    uint2* __restrict__ zb, float* __restrict__ s1s, float* __restrict__ s1d, int N)
{
  const int wave = threadIdx.x >> 6, lane = threadIdx.x & 63;
  const int quad = lane >> 4, l16 = lane & 15;
  const int row0 = blockIdx.x*64 + wave*16;
  if (row0 >= N) return;
  float a1sv[4][4], a1dv[4][4];
#pragma unroll
  for (int hh = 0; hh < 4; hh++)
#pragma unroll
    for (int m = 0; m < 4; m++){
      a1sv[hh][m] = a1[hh*128 + m*16 + l16];
      a1dv[hh][m] = a1[hh*128 + 64 + m*16 + l16];
    }
  const int ar = (row0 + l16 < N) ? (row0 + l16) : (N - 1);   // clamp; dup rows discarded
  floatx4 c[16];
#pragma unroll
  for (int t = 0; t < 16; t++) c[t] = (floatx4){0.f,0.f,0.f,0.f};
#pragma unroll
  for (int ks = 0; ks < 4; ks++){
    const float* ap = &h[(size_t)ar*128 + ks*32 + quad*8];
    float4 v0 = *(const float4*)ap;
    float4 v1 = *(const float4*)(ap + 4);
    float vv[8] = {v0.x,v0.y,v0.z,v0.w,v1.x,v1.y,v1.z,v1.w};
    short8 ahi, alo;
#pragma unroll
    for (int j = 0; j < 8; j++){
      ushort_t hb = f2b(vv[j]);
      float hf = __uint_as_float((uint_t)hb << 16);
      ahi[j] = (short)hb;
      alo[j] = (short)f2b(vv[j] - hf);
    }
#pragma unroll
    for (int t = 0; t < 16; t++){
      short8 b = *(const short8*)&w1bp[(size_t)((t*4 + ks)*64 + lane)*8];
      c[t] = __builtin_amdgcn_mfma_f32_16x16x32_bf16(ahi, b, c[t], 0, 0, 0);
      c[t] = __builtin_amdgcn_mfma_f32_16x16x32_bf16(alo, b, c[t], 0, 0, 0);
    }
  }
#pragma unroll
  for (int i = 0; i < 4; i++){
    const int r = row0 + quad*4 + i;
    if (r >= N) continue;
#pragma unroll
    for (int m = 0; m < 4; m++){
      uint_t w0 = (uint_t)f2b(c[0*4+m][i]) | ((uint_t)f2b(c[1*4+m][i]) << 16);
      uint_t w1 = (uint_t)f2b(c[2*4+m][i]) | ((uint_t)f2b(c[3*4+m][i]) << 16);
      zb[(size_t)r*64 + m*16 + l16] = make_uint2(w0, w1);
    }
#pragma unroll
    for (int hh = 0; hh < 4; hh++){
      float ps = 0.f, pd = 0.f;
#pragma unroll
      for (int m = 0; m < 4; m++){
        float v = c[hh*4+m][i];
        ps += v * a1sv[hh][m];
        pd += v * a1dv[hh][m];
      }
#pragma unroll
      for (int o = 1; o < 16; o <<= 1){
        ps += __shfl_xor(ps, o, 64);
        pd += __shfl_xor(pd, o, 64);
      }
      if (l16 == 0){ s1s[r*4+hh] = ps; s1d[r*4+hh] = pd; }
    }
  }
}

// ---------------- CSR build
__global__ void k_hist(const int* __restrict__ d, int* __restrict__ deg, int E){
  int i = blockIdx.x*256 + threadIdx.x;
  if (i < E) atomicAdd(&deg[d[i]], 1);
}
__global__ __launch_bounds__(256) void k_scan1(const int* __restrict__ deg, int* __restrict__ part){
  __shared__ int tmp[256];
  int t = threadIdx.x;
  tmp[t] = deg[blockIdx.x*256 + t];
  __syncthreads();
  for (int off = 128; off > 0; off >>= 1){
    if (t < off) tmp[t] += tmp[t+off];
    __syncthreads();
  }
  if (t == 0) part[blockIdx.x] = tmp[0];
}
__global__ __launch_bounds__(512) void k_scan2(int* __restrict__ part, int B){
  __shared__ int tmp[512];
  int t = threadIdx.x;
  int v = (t < B) ? part[t] : 0;
  tmp[t] = v; __syncthreads();
  for (int off = 1; off < 512; off <<= 1){
    int x = (t >= off) ? tmp[t-off] : 0;
    __syncthreads();
    tmp[t] += x;
    __syncthreads();
  }
  if (t < B) part[t] = tmp[t] - v;   // exclusive
}
__global__ __launch_bounds__(256) void k_scan3(const int* __restrict__ deg, const int* __restrict__ part,
    int* __restrict__ rowptr, int* __restrict__ cursor){
  __shared__ int tmp[256];
  int t = threadIdx.x, i = blockIdx.x*256 + t;
  int v = deg[i];
  tmp[t] = v; __syncthreads();
  for (int off = 1; off < 256; off <<= 1){
    int x = (t >= off) ? tmp[t-off] : 0;
    __syncthreads();
    tmp[t] += x;
    __syncthreads();
  }
  int excl = tmp[t] - v + part[blockIdx.x];
  rowptr[i] = excl; cursor[i] = excl;
}
__global__ void k_scatter(const int* __restrict__ s, const int* __restrict__ d,
    int* __restrict__ cursor, int* __restrict__ csr, int E){
  int i = blockIdx.x*256 + threadIdx.x;
  if (i < E){
    int p = atomicAdd(&cursor[d[i]], 1);
    csr[p] = s[i];
  }
}

// ---------------- layer1 GAT edge aggregation + ELU -> hneib [N,256] bf16
// pass B: 4 edges/iteration, 16 lanes x 32B per edge row
__global__ __launch_bounds__(256) void k_gat1(
    const uint2* __restrict__ zb, const float* __restrict__ s1src, const float* __restrict__ s1dst,
    const int* __restrict__ rowptr, const int* __restrict__ csr,
    uint2* __restrict__ hneib2, int N)
{
  __shared__ int   sbuf[4][CAP];
  __shared__ __align__(16) float4 ebuf[4][CAP];
  const int wave = threadIdx.x >> 6, lane = threadIdx.x & 63;
  const int dst = blockIdx.x*4 + wave;
  if (dst >= N) return;
  const int beg = rowptr[dst];
  const int deg = rowptr[dst+1] - beg;
  const float4 sd = *(const float4*)&s1dst[dst*4];
  // pass A: exp(e) per edge (scores bounded, exp safe without max shift), denominators
  float t0=0.f,t1=0.f,t2=0.f,t3=0.f;
  for (int j = lane; j < deg; j += 64){
    int s = csr[beg+j];
    float4 sv = *(const float4*)&s1src[s*4];
    float4 a;
    a.x = __expf(lrelu(sv.x+sd.x)); a.y = __expf(lrelu(sv.y+sd.y));
    a.z = __expf(lrelu(sv.z+sd.z)); a.w = __expf(lrelu(sv.w+sd.w));
    if (j < CAP){ sbuf[wave][j] = s; ebuf[wave][j] = a; }
    t0 += a.x; t1 += a.y; t2 += a.z; t3 += a.w;
  }
  const float inv[4] = {1.f/wred_sum(t0), 1.f/wred_sum(t1), 1.f/wred_sum(t2), 1.f/wred_sum(t3)};
  // pass B: 4 edges/iter; group g handles edge jj+g; lane li covers dims 4li..4li+3
  const int g = lane >> 4, li = lane & 15;
  float acc[4][4] = {};   // [local dim d][head]
  int jj = 0;
  if (deg <= CAP){
    for (; jj + 4 <= deg; jj += 4){
      const int j = jj + g;
      int s = sbuf[wave][j]; float4 al = ebuf[wave][j];
      const uint4* zp = (const uint4*)(zb + (size_t)s*64);
      uint4 u0 = zp[2*li], u1 = zp[2*li+1];
      acc[0][0]+=al.x*b2f_lo(u0.x); acc[0][1]+=al.y*b2f_hi(u0.x); acc[0][2]+=al.z*b2f_lo(u0.y); acc[0][3]+=al.w*b2f_hi(u0.y);
      acc[1][0]+=al.x*b2f_lo(u0.z); acc[1][1]+=al.y*b2f_hi(u0.z); acc[1][2]+=al.z*b2f_lo(u0.w); acc[1][3]+=al.w*b2f_hi(u0.w);
      acc[2][0]+=al.x*b2f_lo(u1.x); acc[2][1]+=al.y*b2f_hi(u1.x); acc[2][2]+=al.z*b2f_lo(u1.y); acc[2][3]+=al.w*b2f_hi(u1.y);
      acc[3][0]+=al.x*b2f_lo(u1.z); acc[3][1]+=al.y*b2f_hi(u1.z); acc[3][2]+=al.z*b2f_lo(u1.w); acc[3][3]+=al.w*b2f_hi(u1.w);
    }
    const int r = deg - jj;
    if (r){
      const int j = jj + (g < r ? g : 0);
      int s = sbuf[wave][j]; float4 al = ebuf[wave][j];
      if (g >= r){ al.x=0.f; al.y=0.f; al.z=0.f; al.w=0.f; }
      const uint4* zp = (const uint4*)(zb + (size_t)s*64);
      uint4 u0 = zp[2*li], u1 = zp[2*li+1];
      acc[0][0]+=al.x*b2f_lo(u0.x); acc[0][1]+=al.y*b2f_hi(u0.x); acc[0][2]+=al.z*b2f_lo(u0.y); acc[0][3]+=al.w*b2f_hi(u0.y);
      acc[1][0]+=al.x*b2f_lo(u0.z); acc[1][1]+=al.y*b2f_hi(u0.z); acc[1][2]+=al.z*b2f_lo(u0.w); acc[1][3]+=al.w*b2f_hi(u0.w);
      acc[2][0]+=al.x*b2f_lo(u1.x); acc[2][1]+=al.y*b2f_hi(u1.x); acc[2][2]+=al.z*b2f_lo(u1.y); acc[2][3]+=al.w*b2f_hi(u1.y);
      acc[3][0]+=al.x*b2f_lo(u1.z); acc[3][1]+=al.y*b2f_hi(u1.z); acc[3][2]+=al.z*b2f_lo(u1.w); acc[3][3]+=al.w*b2f_hi(u1.w);
    }
  } else {
    for (; jj < deg; jj += 4){
      const int j = jj + g;
      const bool v = j < deg;
      const int jc = v ? j : jj;
      int s; float4 al;
      if (jc < CAP){ s = sbuf[wave][jc]; al = ebuf[wave][jc]; }
      else {
        s = csr[beg+jc];
        float4 sv = *(const float4*)&s1src[s*4];
        al.x = __expf(lrelu(sv.x+sd.x)); al.y = __expf(lrelu(sv.y+sd.y));
        al.z = __expf(lrelu(sv.z+sd.z)); al.w = __expf(lrelu(sv.w+sd.w));
      }
      if (!v){ al.x=0.f; al.y=0.f; al.z=0.f; al.w=0.f; }
      const uint4* zp = (const uint4*)(zb + (size_t)s*64);
      uint4 u0 = zp[2*li], u1 = zp[2*li+1];
      acc[0][0]+=al.x*b2f_lo(u0.x); acc[0][1]+=al.y*b2f_hi(u0.x); acc[0][2]+=al.z*b2f_lo(u0.y); acc[0][3]+=al.w*b2f_hi(u0.y);
      acc[1][0]+=al.x*b2f_lo(u0.z); acc[1][1]+=al.y*b2f_hi(u0.z); acc[1][2]+=al.z*b2f_lo(u0.w); acc[1][3]+=al.w*b2f_hi(u0.w);
      acc[2][0]+=al.x*b2f_lo(u1.x); acc[2][1]+=al.y*b2f_hi(u1.x); acc[2][2]+=al.z*b2f_lo(u1.y); acc[2][3]+=al.w*b2f_hi(u1.y);
      acc[3][0]+=al.x*b2f_lo(u1.z); acc[3][1]+=al.y*b2f_hi(u1.z); acc[3][2]+=al.z*b2f_lo(u1.w); acc[3][3]+=al.w*b2f_hi(u1.w);
    }
  }
  // combine the 4 edge-groups
#pragma unroll
  for (int d = 0; d < 4; d++)
#pragma unroll
    for (int hh = 0; hh < 4; hh++){
      acc[d][hh] += __shfl_xor(acc[d][hh], 16, 64);
      acc[d][hh] += __shfl_xor(acc[d][hh], 32, 64);
    }
  if (g == 0){
#pragma unroll
    for (int hh = 0; hh < 4; hh++){
      float e0 = acc[0][hh]*inv[hh]; e0 = e0 > 0.f ? e0 : expm1f(e0);
      float e1 = acc[1][hh]*inv[hh]; e1 = e1 > 0.f ? e1 : expm1f(e1);
      float e2 = acc[2][hh]*inv[hh]; e2 = e2 > 0.f ? e2 : expm1f(e2);
      float e3 = acc[3][hh]*inv[hh]; e3 = e3 > 0.f ? e3 : expm1f(e3);
      uint_t w0 = (uint_t)f2b(e0) | ((uint_t)f2b(e1) << 16);   // dims 4li,4li+1
      uint_t w1 = (uint_t)f2b(e2) | ((uint_t)f2b(e3) << 16);   // dims 4li+2,4li+3
      hneib2[(size_t)dst*64 + hh*16 + li] = make_uint2(w0, w1);
    }
  }
}

// ---------------- GEMM2 (MFMA bf16): z2 = hnei @ W2^T, fused scores + bf16 store
__global__ __launch_bounds__(256) void k_gemm2(
    const ushort_t* __restrict__ hneib, const ushort_t* __restrict__ w2bp,
    const float* __restrict__ a2w,
    ushort_t* __restrict__ z2b, float* __restrict__ s2s, float* __restrict__ s2d, int N)
{
  const int wave = threadIdx.x >> 6, lane = threadIdx.x & 63;
  const int quad = lane >> 4, l16 = lane & 15;
  const int strip = blockIdx.x*4 + wave;
  const int nstrips = (N + 15) >> 4;
  if (strip >= nstrips) return;
  const int row0 = strip * 16;
  float a2s[4], a2d[4];
#pragma unroll
  for (int t = 0; t < 4; t++){
    a2s[t] = a2w[t*16 + l16];
    a2d[t] = a2w[64 + t*16 + l16];
  }
  const int ar = (row0 + l16 < N) ? (row0 + l16) : (N - 1);
  floatx4 c[4] = {{0.f,0.f,0.f,0.f},{0.f,0.f,0.f,0.f},{0.f,0.f,0.f,0.f},{0.f,0.f,0.f,0.f}};
#pragma unroll
  for (int ks = 0; ks < 8; ks++){
    short8 a = *(const short8*)&hneib[(size_t)ar*256 + ks*32 + quad*8];
#pragma unroll
    for (int t = 0; t < 4; t++){
      short8 b = *(const short8*)&w2bp[(size_t)((t*8 + ks)*64 + lane)*8];
      c[t] = __builtin_amdgcn_mfma_f32_16x16x32_bf16(a, b, c[t], 0, 0, 0);
    }
  }
#pragma unroll
  for (int i = 0; i < 4; i++){
    const int r = row0 + quad*4 + i;
    float ps = 0.f, pd = 0.f;
    if (r < N){
#pragma unroll
      for (int t = 0; t < 4; t++){
        float v = c[t][i];
        z2b[(size_t)r*64 + t*16 + l16] = f2b(v);
        ps += v * a2s[t]; pd += v * a2d[t];
      }
#pragma unroll
      for (int o = 1; o < 16; o <<= 1){
        ps += __shfl_xor(ps, o, 64);
        pd += __shfl_xor(pd, o, 64);
      }
      if (l16 == 0){ s2s[r] = ps; s2d[r] = pd; }
    }
  }
}

// ---------------- layer2 alphas per CSR slot (wave per dst)
__global__ __launch_bounds__(256) void k_alpha2(
    const float* __restrict__ s2src, const float* __restrict__ s2dst,
    const int* __restrict__ rowptr, const int* __restrict__ csr,
    float* __restrict__ alphaE, int N)
{
  __shared__ float ebuf[4][CAP];
  const int wave = threadIdx.x >> 6, lane = threadIdx.x & 63;
  const int dst = blockIdx.x*4 + wave;
  if (dst >= N) return;
  const int beg = rowptr[dst], deg = rowptr[dst+1] - beg;
  const float sd = s2dst[dst];
  float ts = 0.f;
  for (int j = lane; j < deg; j += 64){
    float a = __expf(lrelu(s2src[csr[beg+j]] + sd));
    if (j < CAP) ebuf[wave][j] = a;
    ts += a;
  }
  const float inv = 1.f/wred_sum(ts);
  for (int j = lane; j < deg; j += 64){
    float a = (j < CAP) ? ebuf[wave][j] : __expf(lrelu(s2src[csr[beg+j]] + sd));
    alphaE[beg+j] = a * inv;
  }
}

// ---------------- layer2 aggregation: edge-parallel global sum of alpha*z2[src]
__global__ __launch_bounds__(256) void k_gat2e(
    const ushort_t* __restrict__ z2b, const float* __restrict__ alphaE,
    const int* __restrict__ csr, float* __restrict__ accOut, int E)
{
  __shared__ __align__(16) float red[4][64];
  const int wave = threadIdx.x >> 6, lane = threadIdx.x & 63;
  const int g = lane >> 4, li = lane & 15;
  float c0=0.f, c1=0.f, c2=0.f, c3=0.f;
  const long long step = (long long)gridDim.x * 16;   // 4 waves/block * 4 edges/wave
  for (long long base = ((long long)blockIdx.x*4 + wave)*4; base < E; base += step){
    const long long e = base + g;
    float al = 0.f; int s = 0;
    if (e < E){ al = alphaE[e]; s = csr[e]; }
    uint2 u = *((const uint2*)(z2b + (size_t)s*64) + li);   // dims 4li..4li+3
    c0 += al * b2f_lo(u.x);
    c1 += al * b2f_hi(u.x);
    c2 += al * b2f_lo(u.y);
    c3 += al * b2f_hi(u.y);
  }
  c0 += __shfl_xor(c0,16,64); c0 += __shfl_xor(c0,32,64);
  c1 += __shfl_xor(c1,16,64); c1 += __shfl_xor(c1,32,64);
  c2 += __shfl_xor(c2,16,64); c2 += __shfl_xor(c2,32,64);
  c3 += __shfl_xor(c3,16,64); c3 += __shfl_xor(c3,32,64);
  if (g == 0) *(float4*)&red[wave][li*4] = make_float4(c0,c1,c2,c3);
  __syncthreads();
  if (wave == 0)
    atomicAdd(&accOut[lane], red[0][lane]+red[1][lane]+red[2][lane]+red[3][lane]);
}

// ---------------- fractal: acc[s][k] = sum_n h[fcm[n,s]][k]   (exact f32)
__global__ __launch_bounds__(256) void k_frac(const float* __restrict__ h,
    const int* __restrict__ fcm, float* __restrict__ accFrac, int N)
{
  __shared__ float red[4][6][64];
  const int wave = threadIdx.x >> 6, lane = threadIdx.x & 63;
  float a[6] = {0.f,0.f,0.f,0.f,0.f,0.f};
  const int stride = gridDim.x * 4;
  for (int n = blockIdx.x*4 + wave; n < N; n += stride){
    int i0 = fcm[n*3], i1 = fcm[n*3+1], i2 = fcm[n*3+2];
    a[0] += h[(size_t)i0*128 + lane]; a[1] += h[(size_t)i0*128 + 64 + lane];
    a[2] += h[(size_t)i1*128 + lane]; a[3] += h[(size_t)i1*128 + 64 + lane];
    a[4] += h[(size_t)i2*128 + lane]; a[5] += h[(size_t)i2*128 + 64 + lane];
  }
#pragma unroll
  for (int q = 0; q < 6; q++) red[wave][q][lane] = a[q];
  __syncthreads();
  if (wave == 0){
#pragma unroll
    for (int q = 0; q < 6; q++){
      float v = red[0][q][lane]+red[1][q][lane]+red[2][q][lane]+red[3][q][lane];
      atomicAdd(&accFrac[(q>>1)*128 + (q&1)*64 + lane], v);
    }
  }
}

// ---------------- finalize
__global__ __launch_bounds__(256) void k_finalize(const float* __restrict__ acc,
    const float* __restrict__ frw, const float* __restrict__ frf,
    const float* __restrict__ fc2, float* __restrict__ out, float invN)
{
  __shared__ float g[384], mm[192], hfrac[64], nei[64];
  int t = threadIdx.x;
  for (int i = t; i < 384; i += 256) g[i] = acc[64 + i] * invN;
  if (t < 64) nei[t] = acc[t] * invN;
  __syncthreads();
  for (int i = t; i < 192; i += 256){
    int s = i >> 6, d = i & 63;
    const float* w = frw + (size_t)(s*64 + d)*128;
    const float* gs = g + s*128;
    float sum = 0.f;
    for (int k = 0; k < 128; k++) sum += gs[k]*w[k];
    mm[i] = sum;
  }
  __syncthreads();
  if (t < 64){
    float s = 0.f;
    for (int k = 0; k < 192; k++) s += mm[k]*frf[t*192 + k];
    hfrac[t] = s;
  }
  __syncthreads();
  if (t < 64){
    float o = 0.f;
    for (int k = 0; k < 64; k++)
      o += fc2[t*128 + k]*nei[k] + fc2[t*128 + 64 + k]*hfrac[k];
    out[t] = o;
  }
}

extern "C" void kernel_launch(void* const* d_in, const int* in_sizes, int n_in,
                              void* d_out, int out_size, void* d_ws, size_t ws_size,
                              hipStream_t stream)
{
  const float* h    = (const float*)d_in[0];
  const int*   srcI = (const int*)  d_in[1];
  const int*   dstI = (const int*)  d_in[2];
  const int*   fcm  = (const int*)  d_in[3];
  const float* l1fc = (const float*)d_in[4];
  const float* l1at = (const float*)d_in[5];
  const float* l2fc = (const float*)d_in[6];
  const float* l2at = (const float*)d_in[7];
  const float* frw  = (const float*)d_in[8];
  const float* frf  = (const float*)d_in[9];
  const float* fc2  = (const float*)d_in[10];
  float* out = (float*)d_out;
  (void)n_in; (void)out_size; (void)ws_size;

  const int N = in_sizes[0] / 128;
  const int E = in_sizes[1];
  const int B = (N + 256) / 256;     // ceil((N+1)/256) so rowptr[N] is covered
  const int PAD = B * 256;

  char* w = (char*)d_ws;
  size_t off = 0;
  auto alloc = [&](size_t bytes) -> char* {
    char* p = w + off; off = (off + bytes + 255) & ~(size_t)255; return p;
  };
  uint2*    zb    = (uint2*)   alloc((size_t)N*64*8);   // 51.2 MB packed bf16 z
  uint2*    hneib = (uint2*)   alloc((size_t)N*64*8);   // 51.2 MB packed bf16 hnei [N,256]
  ushort_t* z2b   = (ushort_t*)alloc((size_t)N*64*2);   // 12.8 MB bf16 z2
  float* s1s  = (float*)alloc((size_t)N*4*4);
  float* s1d  = (float*)alloc((size_t)N*4*4);
  float* s2s  = (float*)alloc((size_t)N*4);
  float* s2d  = (float*)alloc((size_t)N*4);
  float* alphaE = (float*)alloc((size_t)E*4);           // 6.8 MB
  int*   deg    = (int*)alloc((size_t)PAD*4);
  int*   rowptr = (int*)alloc((size_t)PAD*4);
  int*   cursor = (int*)alloc((size_t)PAD*4);
  int*   part   = (int*)alloc(512*4);
  int*   csr    = (int*)alloc((size_t)E*4);
  ushort_t* w1bp = (ushort_t*)alloc(32768*2);
  ushort_t* w2bp = (ushort_t*)alloc(16384*2);
  float* acc    = (float*)alloc(448*4);   // [0:64) nei2-sum, [64:448) frac-sum

  hipMemsetAsync(deg, 0, (size_t)PAD*4, stream);
  hipMemsetAsync(acc, 0, 448*4, stream);

  hipLaunchKernelGGL(k_wpack,   dim3(192),           dim3(256), 0, stream, l1fc, l2fc, w1bp, w2bp);
  hipLaunchKernelGGL(k_hist,    dim3((E+255)/256),   dim3(256), 0, stream, dstI, deg, E);
  hipLaunchKernelGGL(k_scan1,   dim3(B),             dim3(256), 0, stream, deg, part);
  hipLaunchKernelGGL(k_scan2,   dim3(1),             dim3(512), 0, stream, part, B);
  hipLaunchKernelGGL(k_scan3,   dim3(B),             dim3(256), 0, stream, deg, part, rowptr, cursor);
  hipLaunchKernelGGL(k_scatter, dim3((E+255)/256),   dim3(256), 0, stream, srcI, dstI, cursor, csr, E);
  hipLaunchKernelGGL(k_gemm1m,  dim3((N+63)/64),     dim3(256), 0, stream,
                     h, w1bp, l1at, zb, s1s, s1d, N);
  hipLaunchKernelGGL(k_gat1,    dim3((N+3)/4),       dim3(256), 0, stream,
                     zb, s1s, s1d, rowptr, csr, hneib, N);
  hipLaunchKernelGGL(k_gemm2,   dim3(((N+15)/16+3)/4), dim3(256), 0, stream,
                     (const ushort_t*)hneib, w2bp, l2at, z2b, s2s, s2d, N);
  hipLaunchKernelGGL(k_alpha2,  dim3((N+3)/4),       dim3(256), 0, stream,
                     s2s, s2d, rowptr, csr, alphaE, N);
  hipLaunchKernelGGL(k_gat2e,   dim3(2048),          dim3(256), 0, stream,
                     z2b, alphaE, csr, acc, E);
  hipLaunchKernelGGL(k_frac,    dim3(1024),          dim3(256), 0, stream, h, fcm, acc + 64, N);
  hipLaunchKernelGGL(k_finalize,dim3(1),             dim3(256), 0, stream,
                     acc, frw, frf, fc2, out, 1.0f/(float)N);
}

// Round 7
// 656.093 us; speedup vs baseline: 1.0222x; 1.0222x over previous
//
#include <hip/hip_runtime.h>
#include <math.h>

// GAT pipeline. bf16-packed z/hnei/z2; no-max softmax; MFMA GEMMs with
// LDS-staged B (GEMM1 incl. a 17th "score" tile: s = h @ (W1^T a1), so layer1
// scores come out of the same MFMA pass); gat1 = R5's 2-edge gather variant.

#define CAP 128   // per-wave LDS edge cache; deg>CAP falls back to recompute

typedef unsigned int  uint_t;
typedef unsigned short ushort_t;
typedef __attribute__((ext_vector_type(8))) short short8;
typedef __attribute__((ext_vector_type(4))) float floatx4;

__device__ __forceinline__ float wred_sum(float v){
#pragma unroll
  for (int o = 1; o < 64; o <<= 1) v += __shfl_xor(v, o, 64);
  return v;
}
__device__ __forceinline__ float lrelu(float x){ return x >= 0.f ? x : 0.01f*x; }
__device__ __forceinline__ ushort_t f2b(float f){
  uint_t u = __float_as_uint(f);
  u = (u + 0x7FFFu + ((u >> 16) & 1u)) >> 16;   // RNE
  return (ushort_t)u;
}
__device__ __forceinline__ float b2f_lo(uint_t w){ return __uint_as_float(w << 16); }
__device__ __forceinline__ float b2f_hi(uint_t w){ return __uint_as_float(w & 0xFFFF0000u); }

// ---------------- pack W1 (tiles 0..15) + score tile (16) + W2, one kernel
// blocks 0..127: W1 z-tiles; 128..191: W2; 192: score-vector tile
__global__ void k_wpack(const float* __restrict__ W1, const float* __restrict__ W2,
                        const float* __restrict__ a1,
                        ushort_t* __restrict__ w1bp, ushort_t* __restrict__ w2bp){
  __shared__ float v[8][128];
  const int bx = blockIdx.x, t = threadIdx.x;
  if (bx < 128){
    int idx = bx*256 + t;
    int j = idx & 7, lane = (idx >> 3) & 63, ks = (idx >> 9) & 3, tt = idx >> 11;
    int n = tt*16 + (lane & 15), k = ks*32 + (lane >> 4)*8 + j;
    w1bp[idx] = f2b(W1[n*128 + k]);
  } else if (bx < 192){
    int i2 = (bx-128)*256 + t;
    int j = i2 & 7, lane = (i2 >> 3) & 63, ks = (i2 >> 9) & 7, tt = i2 >> 12;
    int n = tt*16 + (lane & 15), k = ks*32 + (lane >> 4)*8 + j;
    w2bp[i2] = f2b(W2[n*256 + k]);
  } else {
    // v[col][k]: col 0..3 = src score vec per head, 4..7 = dst
    for (int o = t; o < 1024; o += 256){
      int col = o >> 7, k = o & 127, hh = col & 3, off = (col >> 2)*64;
      float s = 0.f;
      for (int n = 0; n < 64; n++) s += a1[hh*128 + off + n] * W1[(hh*64 + n)*128 + k];
      v[col][k] = s;
    }
    __syncthreads();
    for (int idx = t; idx < 2048; idx += 256){
      int j = idx & 7, lane = (idx >> 3) & 63, ks = idx >> 9;
      int col = lane & 15, k = ks*32 + (lane >> 4)*8 + j;
      w1bp[32768 + idx] = (col < 8) ? f2b(v[col][k]) : (ushort_t)0;
    }
  }
}

// ---------------- GEMM1 (MFMA, split-A, LDS-staged B): zb + layer1 scores
// 512 threads = 8 waves; block covers 128 rows; B (17 tiles x K=128) in LDS.
__global__ __launch_bounds__(512) void k_gemm1m(const float* __restrict__ h,
    const ushort_t* __restrict__ w1bp,
    uint2* __restrict__ zb, float* __restrict__ s1s, float* __restrict__ s1d, int N)
{
  __shared__ __align__(16) ushort_t ldsB[34816];   // 69,632 B
  const int tid = threadIdx.x;
  {
    const uint4* src = (const uint4*)w1bp;
    uint4* dst = (uint4*)ldsB;
    for (int i = tid; i < 4352; i += 512) dst[i] = src[i];
  }
  __syncthreads();
  const int wave = tid >> 6, lane = tid & 63;
  const int quad = lane >> 4, l16 = lane & 15;
  const int row0 = blockIdx.x*128 + wave*16;
  if (row0 >= N) return;
  const int ar = (row0 + l16 < N) ? (row0 + l16) : (N - 1);   // clamp; dups discarded
  floatx4 c[17];
#pragma unroll
  for (int t = 0; t < 17; t++) c[t] = (floatx4){0.f,0.f,0.f,0.f};
#pragma unroll
  for (int ks = 0; ks < 4; ks++){
    const float* ap = &h[(size_t)ar*128 + ks*32 + quad*8];
    float4 v0 = *(const float4*)ap;
    float4 v1 = *(const float4*)(ap + 4);
    float vv[8] = {v0.x,v0.y,v0.z,v0.w,v1.x,v1.y,v1.z,v1.w};
    short8 ahi, alo;
#pragma unroll
    for (int j = 0; j < 8; j++){
      ushort_t hb = f2b(vv[j]);
      float hf = __uint_as_float((uint_t)hb << 16);
      ahi[j] = (short)hb;
      alo[j] = (short)f2b(vv[j] - hf);
    }
#pragma unroll
    for (int t = 0; t < 17; t++){
      short8 b = *(const short8*)&ldsB[(size_t)((t*4 + ks)*64 + lane)*8];
      c[t] = __builtin_amdgcn_mfma_f32_16x16x32_bf16(ahi, b, c[t], 0, 0, 0);
      c[t] = __builtin_amdgcn_mfma_f32_16x16x32_bf16(alo, b, c[t], 0, 0, 0);
    }
  }
  // epilogue: C layout col = tile*16 + l16, row = row0 + quad*4 + i
#pragma unroll
  for (int i = 0; i < 4; i++){
    const int r = row0 + quad*4 + i;
    if (r >= N) continue;
#pragma unroll
    for (int m = 0; m < 4; m++){
      uint_t w0 = (uint_t)f2b(c[0*4+m][i]) | ((uint_t)f2b(c[1*4+m][i]) << 16);
      uint_t w1 = (uint_t)f2b(c[2*4+m][i]) | ((uint_t)f2b(c[3*4+m][i]) << 16);
      zb[(size_t)r*64 + m*16 + l16] = make_uint2(w0, w1);
    }
    const float sv = c[16][i];
    if (l16 < 4) s1s[r*4 + l16] = sv;
    else if (l16 < 8) s1d[r*4 + (l16 - 4)] = sv;
  }
}

// ---------------- CSR build
__global__ void k_hist(const int* __restrict__ d, int* __restrict__ deg, int E){
  int i = blockIdx.x*256 + threadIdx.x;
  if (i < E) atomicAdd(&deg[d[i]], 1);
}
__global__ __launch_bounds__(256) void k_scan1(const int* __restrict__ deg, int* __restrict__ part){
  __shared__ int tmp[256];
  int t = threadIdx.x;
  tmp[t] = deg[blockIdx.x*256 + t];
  __syncthreads();
  for (int off = 128; off > 0; off >>= 1){
    if (t < off) tmp[t] += tmp[t+off];
    __syncthreads();
  }
  if (t == 0) part[blockIdx.x] = tmp[0];
}
__global__ __launch_bounds__(512) void k_scan2(int* __restrict__ part, int B){
  __shared__ int tmp[512];
  int t = threadIdx.x;
  int v = (t < B) ? part[t] : 0;
  tmp[t] = v; __syncthreads();
  for (int off = 1; off < 512; off <<= 1){
    int x = (t >= off) ? tmp[t-off] : 0;
    __syncthreads();
    tmp[t] += x;
    __syncthreads();
  }
  if (t < B) part[t] = tmp[t] - v;   // exclusive
}
__global__ __launch_bounds__(256) void k_scan3(const int* __restrict__ deg, const int* __restrict__ part,
    int* __restrict__ rowptr, int* __restrict__ cursor){
  __shared__ int tmp[256];
  int t = threadIdx.x, i = blockIdx.x*256 + t;
  int v = deg[i];
  tmp[t] = v; __syncthreads();
  for (int off = 1; off < 256; off <<= 1){
    int x = (t >= off) ? tmp[t-off] : 0;
    __syncthreads();
    tmp[t] += x;
    __syncthreads();
  }
  int excl = tmp[t] - v + part[blockIdx.x];
  rowptr[i] = excl; cursor[i] = excl;
}
__global__ void k_scatter(const int* __restrict__ s, const int* __restrict__ d,
    int* __restrict__ cursor, int* __restrict__ csr, int E){
  int i = blockIdx.x*256 + threadIdx.x;
  if (i < E){
    int p = atomicAdd(&cursor[d[i]], 1);
    csr[p] = s[i];
  }
}

// ---------------- layer1 GAT edge aggregation + ELU -> hneib [N,256] bf16
// (R5 2-edge variant: 32 lanes x uint4 per edge row)
__global__ __launch_bounds__(256) void k_gat1(
    const uint2* __restrict__ zb, const float* __restrict__ s1src, const float* __restrict__ s1dst,
    const int* __restrict__ rowptr, const int* __restrict__ csr,
    uint_t* __restrict__ hneib, int N)
{
  __shared__ int   sbuf[4][CAP];
  __shared__ __align__(16) float4 ebuf[4][CAP];
  const int wave = threadIdx.x >> 6, lane = threadIdx.x & 63;
  const int dst = blockIdx.x*4 + wave;
  if (dst >= N) return;
  const int beg = rowptr[dst];
  const int deg = rowptr[dst+1] - beg;
  const float4 sd = *(const float4*)&s1dst[dst*4];
  float t0=0.f,t1=0.f,t2=0.f,t3=0.f;
  for (int j = lane; j < deg; j += 64){
    int s = csr[beg+j];
    float4 sv = *(const float4*)&s1src[s*4];
    float4 a;
    a.x = __expf(lrelu(sv.x+sd.x)); a.y = __expf(lrelu(sv.y+sd.y));
    a.z = __expf(lrelu(sv.z+sd.z)); a.w = __expf(lrelu(sv.w+sd.w));
    if (j < CAP){ sbuf[wave][j] = s; ebuf[wave][j] = a; }
    t0 += a.x; t1 += a.y; t2 += a.z; t3 += a.w;
  }
  const float i0 = 1.f/wred_sum(t0), i1 = 1.f/wred_sum(t1);
  const float i2 = 1.f/wred_sum(t2), i3 = 1.f/wred_sum(t3);
  const int eh = lane >> 5, li = lane & 31;
  float acc[2][4] = {};
  int jj = 0;
  if (deg <= CAP){
    for (; jj + 2 <= deg; jj += 2){
      const int j = jj + eh;
      int s = sbuf[wave][j]; float4 al = ebuf[wave][j];
      uint4 u = *((const uint4*)(zb + (size_t)s*64) + li);
      acc[0][0] += al.x * b2f_lo(u.x);
      acc[0][1] += al.y * b2f_hi(u.x);
      acc[0][2] += al.z * b2f_lo(u.y);
      acc[0][3] += al.w * b2f_hi(u.y);
      acc[1][0] += al.x * b2f_lo(u.z);
      acc[1][1] += al.y * b2f_hi(u.z);
      acc[1][2] += al.z * b2f_lo(u.w);
      acc[1][3] += al.w * b2f_hi(u.w);
    }
    if (jj < deg && eh == 0){
      int s = sbuf[wave][jj]; float4 al = ebuf[wave][jj];
      uint4 u = *((const uint4*)(zb + (size_t)s*64) + li);
      acc[0][0] += al.x * b2f_lo(u.x);
      acc[0][1] += al.y * b2f_hi(u.x);
      acc[0][2] += al.z * b2f_lo(u.y);
      acc[0][3] += al.w * b2f_hi(u.y);
      acc[1][0] += al.x * b2f_lo(u.z);
      acc[1][1] += al.y * b2f_hi(u.z);
      acc[1][2] += al.z * b2f_lo(u.w);
      acc[1][3] += al.w * b2f_hi(u.w);
    }
  } else {
    for (; jj < deg; jj += 2){
      const int j = jj + eh;
      const bool v = j < deg;
      const int jc = v ? j : jj;
      int s; float4 al;
      if (jc < CAP){ s = sbuf[wave][jc]; al = ebuf[wave][jc]; }
      else {
        s = csr[beg+jc];
        float4 sv = *(const float4*)&s1src[s*4];
        al.x = __expf(lrelu(sv.x+sd.x)); al.y = __expf(lrelu(sv.y+sd.y));
        al.z = __expf(lrelu(sv.z+sd.z)); al.w = __expf(lrelu(sv.w+sd.w));
      }
      if (!v){ al.x=0.f; al.y=0.f; al.z=0.f; al.w=0.f; }
      uint4 u = *((const uint4*)(zb + (size_t)s*64) + li);
      acc[0][0] += al.x * b2f_lo(u.x);
      acc[0][1] += al.y * b2f_hi(u.x);
      acc[0][2] += al.z * b2f_lo(u.y);
      acc[0][3] += al.w * b2f_hi(u.y);
      acc[1][0] += al.x * b2f_lo(u.z);
      acc[1][1] += al.y * b2f_hi(u.z);
      acc[1][2] += al.z * b2f_lo(u.w);
      acc[1][3] += al.w * b2f_hi(u.w);
    }
  }
#pragma unroll
  for (int k = 0; k < 2; k++)
#pragma unroll
    for (int hh = 0; hh < 4; hh++) acc[k][hh] += __shfl_xor(acc[k][hh], 32, 64);
  if (eh == 0){
    const float inv[4] = {i0, i1, i2, i3};
#pragma unroll
    for (int hh = 0; hh < 4; hh++){
      float v0 = acc[0][hh]*inv[hh]; v0 = v0 > 0.f ? v0 : expm1f(v0);
      float v1 = acc[1][hh]*inv[hh]; v1 = v1 > 0.f ? v1 : expm1f(v1);
      hneib[(size_t)dst*128 + hh*32 + li] = (uint_t)f2b(v0) | ((uint_t)f2b(v1) << 16);
    }
  }
}

// ---------------- GEMM2 (MFMA bf16): z2 = hnei @ W2^T, fused scores + bf16 store
__global__ __launch_bounds__(256) void k_gemm2(
    const ushort_t* __restrict__ hneib, const ushort_t* __restrict__ w2bp,
    const float* __restrict__ a2w,
    ushort_t* __restrict__ z2b, float* __restrict__ s2s, float* __restrict__ s2d, int N)
{
  const int wave = threadIdx.x >> 6, lane = threadIdx.x & 63;
  const int quad = lane >> 4, l16 = lane & 15;
  const int strip = blockIdx.x*4 + wave;
  const int nstrips = (N + 15) >> 4;
  if (strip >= nstrips) return;
  const int row0 = strip * 16;
  float a2s[4], a2d[4];
#pragma unroll
  for (int t = 0; t < 4; t++){
    a2s[t] = a2w[t*16 + l16];
    a2d[t] = a2w[64 + t*16 + l16];
  }
  const int ar = (row0 + l16 < N) ? (row0 + l16) : (N - 1);
  floatx4 c[4] = {{0.f,0.f,0.f,0.f},{0.f,0.f,0.f,0.f},{0.f,0.f,0.f,0.f},{0.f,0.f,0.f,0.f}};
#pragma unroll
  for (int ks = 0; ks < 8; ks++){
    short8 a = *(const short8*)&hneib[(size_t)ar*256 + ks*32 + quad*8];
#pragma unroll
    for (int t = 0; t < 4; t++){
      short8 b = *(const short8*)&w2bp[(size_t)((t*8 + ks)*64 + lane)*8];
      c[t] = __builtin_amdgcn_mfma_f32_16x16x32_bf16(a, b, c[t], 0, 0, 0);
    }
  }
#pragma unroll
  for (int i = 0; i < 4; i++){
    const int r = row0 + quad*4 + i;
    float ps = 0.f, pd = 0.f;
    if (r < N){
#pragma unroll
      for (int t = 0; t < 4; t++){
        float v = c[t][i];
        z2b[(size_t)r*64 + t*16 + l16] = f2b(v);
        ps += v * a2s[t]; pd += v * a2d[t];
      }
#pragma unroll
      for (int o = 1; o < 16; o <<= 1){
        ps += __shfl_xor(ps, o, 64);
        pd += __shfl_xor(pd, o, 64);
      }
      if (l16 == 0){ s2s[r] = ps; s2d[r] = pd; }
    }
  }
}

// ---------------- layer2 alphas per CSR slot (wave per dst)
__global__ __launch_bounds__(256) void k_alpha2(
    const float* __restrict__ s2src, const float* __restrict__ s2dst,
    const int* __restrict__ rowptr, const int* __restrict__ csr,
    float* __restrict__ alphaE, int N)
{
  __shared__ float ebuf[4][CAP];
  const int wave = threadIdx.x >> 6, lane = threadIdx.x & 63;
  const int dst = blockIdx.x*4 + wave;
  if (dst >= N) return;
  const int beg = rowptr[dst], deg = rowptr[dst+1] - beg;
  const float sd = s2dst[dst];
  float ts = 0.f;
  for (int j = lane; j < deg; j += 64){
    float a = __expf(lrelu(s2src[csr[beg+j]] + sd));
    if (j < CAP) ebuf[wave][j] = a;
    ts += a;
  }
  const float inv = 1.f/wred_sum(ts);
  for (int j = lane; j < deg; j += 64){
    float a = (j < CAP) ? ebuf[wave][j] : __expf(lrelu(s2src[csr[beg+j]] + sd));
    alphaE[beg+j] = a * inv;
  }
}

// ---------------- layer2 aggregation: edge-parallel global sum of alpha*z2[src]
__global__ __launch_bounds__(256) void k_gat2e(
    const ushort_t* __restrict__ z2b, const float* __restrict__ alphaE,
    const int* __restrict__ csr, float* __restrict__ accOut, int E)
{
  __shared__ __align__(16) float red[4][64];
  const int wave = threadIdx.x >> 6, lane = threadIdx.x & 63;
  const int g = lane >> 4, li = lane & 15;
  float c0=0.f, c1=0.f, c2=0.f, c3=0.f;
  const long long step = (long long)gridDim.x * 16;
  for (long long base = ((long long)blockIdx.x*4 + wave)*4; base < E; base += step){
    const long long e = base + g;
    float al = 0.f; int s = 0;
    if (e < E){ al = alphaE[e]; s = csr[e]; }
    uint2 u = *((const uint2*)(z2b + (size_t)s*64) + li);
    c0 += al * b2f_lo(u.x);
    c1 += al * b2f_hi(u.x);
    c2 += al * b2f_lo(u.y);
    c3 += al * b2f_hi(u.y);
  }
  c0 += __shfl_xor(c0,16,64); c0 += __shfl_xor(c0,32,64);
  c1 += __shfl_xor(c1,16,64); c1 += __shfl_xor(c1,32,64);
  c2 += __shfl_xor(c2,16,64); c2 += __shfl_xor(c2,32,64);
  c3 += __shfl_xor(c3,16,64); c3 += __shfl_xor(c3,32,64);
  if (g == 0) *(float4*)&red[wave][li*4] = make_float4(c0,c1,c2,c3);
  __syncthreads();
  if (wave == 0)
    atomicAdd(&accOut[lane], red[0][lane]+red[1][lane]+red[2][lane]+red[3][lane]);
}

// ---------------- fractal: acc[s][k] = sum_n h[fcm[n,s]][k]   (exact f32)
__global__ __launch_bounds__(256) void k_frac(const float* __restrict__ h,
    const int* __restrict__ fcm, float* __restrict__ accFrac, int N)
{
  __shared__ float red[4][6][64];
  const int wave = threadIdx.x >> 6, lane = threadIdx.x & 63;
  float a[6] = {0.f,0.f,0.f,0.f,0.f,0.f};
  const int stride = gridDim.x * 4;
  for (int n = blockIdx.x*4 + wave; n < N; n += stride){
    int i0 = fcm[n*3], i1 = fcm[n*3+1], i2 = fcm[n*3+2];
    a[0] += h[(size_t)i0*128 + lane]; a[1] += h[(size_t)i0*128 + 64 + lane];
    a[2] += h[(size_t)i1*128 + lane]; a[3] += h[(size_t)i1*128 + 64 + lane];
    a[4] += h[(size_t)i2*128 + lane]; a[5] += h[(size_t)i2*128 + 64 + lane];
  }
#pragma unroll
  for (int q = 0; q < 6; q++) red[wave][q][lane] = a[q];
  __syncthreads();
  if (wave == 0){
#pragma unroll
    for (int q = 0; q < 6; q++){
      float v = red[0][q][lane]+red[1][q][lane]+red[2][q][lane]+red[3][q][lane];
      atomicAdd(&accFrac[(q>>1)*128 + (q&1)*64 + lane], v);
    }
  }
}

// ---------------- finalize
__global__ __launch_bounds__(256) void k_finalize(const float* __restrict__ acc,
    const float* __restrict__ frw, const float* __restrict__ frf,
    const float* __restrict__ fc2, float* __restrict__ out, float invN)
{
  __shared__ float g[384], mm[192], hfrac[64], nei[64];
  int t = threadIdx.x;
  for (int i = t; i < 384; i += 256) g[i] = acc[64 + i] * invN;
  if (t < 64) nei[t] = acc[t] * invN;
  __syncthreads();
  for (int i = t; i < 192; i += 256){
    int s = i >> 6, d = i & 63;
    const float* w = frw + (size_t)(s*64 + d)*128;
    const float* gs = g + s*128;
    float sum = 0.f;
    for (int k = 0; k < 128; k++) sum += gs[k]*w[k];
    mm[i] = sum;
  }
  __syncthreads();
  if (t < 64){
    float s = 0.f;
    for (int k = 0; k < 192; k++) s += mm[k]*frf[t*192 + k];
    hfrac[t] = s;
  }
  __syncthreads();
  if (t < 64){
    float o = 0.f;
    for (int k = 0; k < 64; k++)
      o += fc2[t*128 + k]*nei[k] + fc2[t*128 + 64 + k]*hfrac[k];
    out[t] = o;
  }
}

extern "C" void kernel_launch(void* const* d_in, const int* in_sizes, int n_in,
                              void* d_out, int out_size, void* d_ws, size_t ws_size,
                              hipStream_t stream)
{
  const float* h    = (const float*)d_in[0];
  const int*   srcI = (const int*)  d_in[1];
  const int*   dstI = (const int*)  d_in[2];
  const int*   fcm  = (const int*)  d_in[3];
  const float* l1fc = (const float*)d_in[4];
  const float* l1at = (const float*)d_in[5];
  const float* l2fc = (const float*)d_in[6];
  const float* l2at = (const float*)d_in[7];
  const float* frw  = (const float*)d_in[8];
  const float* frf  = (const float*)d_in[9];
  const float* fc2  = (const float*)d_in[10];
  float* out = (float*)d_out;
  (void)n_in; (void)out_size; (void)ws_size;

  const int N = in_sizes[0] / 128;
  const int E = in_sizes[1];
  const int B = (N + 256) / 256;     // ceil((N+1)/256) so rowptr[N] is covered
  const int PAD = B * 256;

  char* w = (char*)d_ws;
  size_t off = 0;
  auto alloc = [&](size_t bytes) -> char* {
    char* p = w + off; off = (off + bytes + 255) & ~(size_t)255; return p;
  };
  uint2*    zb    = (uint2*)   alloc((size_t)N*64*8);   // 51.2 MB packed bf16 z
  uint_t*   hneib = (uint_t*)  alloc((size_t)N*128*4);  // 51.2 MB packed bf16 hnei [N,256]
  ushort_t* z2b   = (ushort_t*)alloc((size_t)N*64*2);   // 12.8 MB bf16 z2
  float* s1s  = (float*)alloc((size_t)N*4*4);
  float* s1d  = (float*)alloc((size_t)N*4*4);
  float* s2s  = (float*)alloc((size_t)N*4);
  float* s2d  = (float*)alloc((size_t)N*4);
  float* alphaE = (float*)alloc((size_t)E*4);
  int*   deg    = (int*)alloc((size_t)PAD*4);
  int*   rowptr = (int*)alloc((size_t)PAD*4);
  int*   cursor = (int*)alloc((size_t)PAD*4);
  int*   part   = (int*)alloc(512*4);
  int*   csr    = (int*)alloc((size_t)E*4);
  ushort_t* w1bp = (ushort_t*)alloc(34816*2);   // 16 z-tiles + 1 score tile
  ushort_t* w2bp = (ushort_t*)alloc(16384*2);
  float* acc    = (float*)alloc(448*4);   // [0:64) nei2-sum, [64:448) frac-sum

  hipMemsetAsync(deg, 0, (size_t)PAD*4, stream);
  hipMemsetAsync(acc, 0, 448*4, stream);

  hipLaunchKernelGGL(k_wpack,   dim3(193),           dim3(256), 0, stream,
                     l1fc, l2fc, l1at, w1bp, w2bp);
  hipLaunchKernelGGL(k_hist,    dim3((E+255)/256),   dim3(256), 0, stream, dstI, deg, E);
  hipLaunchKernelGGL(k_scan1,   dim3(B),             dim3(256), 0, stream, deg, part);
  hipLaunchKernelGGL(k_scan2,   dim3(1),             dim3(512), 0, stream, part, B);
  hipLaunchKernelGGL(k_scan3,   dim3(B),             dim3(256), 0, stream, deg, part, rowptr, cursor);
  hipLaunchKernelGGL(k_scatter, dim3((E+255)/256),   dim3(256), 0, stream, srcI, dstI, cursor, csr, E);
  hipLaunchKernelGGL(k_gemm1m,  dim3((N+127)/128),   dim3(512), 0, stream,
                     h, w1bp, zb, s1s, s1d, N);
  hipLaunchKernelGGL(k_gat1,    dim3((N+3)/4),       dim3(256), 0, stream,
                     zb, s1s, s1d, rowptr, csr, hneib, N);
  hipLaunchKernelGGL(k_gemm2,   dim3(((N+15)/16+3)/4), dim3(256), 0, stream,
                     (const ushort_t*)hneib, w2bp, l2at, z2b, s2s, s2d, N);
  hipLaunchKernelGGL(k_alpha2,  dim3((N+3)/4),       dim3(256), 0, stream,
                     s2s, s2d, rowptr, csr, alphaE, N);
  hipLaunchKernelGGL(k_gat2e,   dim3(2048),          dim3(256), 0, stream,
                     z2b, alphaE, csr, acc, E);
  hipLaunchKernelGGL(k_frac,    dim3(1024),          dim3(256), 0, stream, h, fcm, acc + 64, N);
  hipLaunchKernelGGL(k_finalize,dim3(1),             dim3(256), 0, stream,
                     acc, frw, frf, fc2, out, 1.0f/(float)N);
}